// Round 6
// baseline (238.482 us; speedup 1.0000x reference)
//
#include <hip/hip_runtime.h>
#include <hip/hip_cooperative_groups.h>

namespace cg = cooperative_groups;

// Chamfer distance: B=8, N=M=8192, D=3, fp32, via bf16 split-precision MFMA.
// R13: R12 post-mortem: partial is parked at ~52us (best[] stays AGPR-side,
//   VALU ~17.7us vs 6.8 floor), but the BIGGER cost is structural: every
//   round shows ~50us of non-partial time (R7 95.5/45.4, R9 100.1/48.3,
//   R12 102.4/52.0) with prep being ~3us of real work. R6->R7 already
//   demonstrated ~25us per graph node. So: fuse prep+partial into ONE
//   cooperative kernel (grid-wide sync between pack and stream phases).
//   - grid 16x64=1024 blocks @ launch_bounds(256,4): <=128 unified regs
//     -> 4 blocks/CU capacity (LDS 16.9KB allows 9) -> co-resident -> legal
//     cooperative launch.
//   - phase1: gid<2*B*N packs bpack (same mapping as old prep), out=0.
//     __threadfence(), afrag compute (raw inputs only) overlaps sync.
//   - grid.sync(), then the UNCHANGED R12 streaming body.
//   - fallback: if cooperative enqueue fails at capture, use the proven
//     two-kernel path.

#define B_DIM 8
#define N_DIM 8192
#define MT    (N_DIM / 32)      // 256 m-tiles per (dir,b)
#define BLOCK 256
#define PPW   2                 // n-tiles per wave

typedef short  bf16x8 __attribute__((ext_vector_type(8)));
typedef float  f32x16 __attribute__((ext_vector_type(16)));

__device__ __forceinline__ unsigned short bf16_rne(float f) {
    unsigned int u = __float_as_uint(f);
    u += 0x7fffu + ((u >> 16) & 1u);
    return (unsigned short)(u >> 16);
}
__device__ __forceinline__ float bf16f(unsigned short h) {
    return __uint_as_float(((unsigned int)h) << 16);
}

// ---- phase-1 helper: pack one point's B-fragment pair --------------------
__device__ __forceinline__ void pack_point(
    const float* __restrict__ pred, const float* __restrict__ gt,
    unsigned short* __restrict__ bpack, int i)
{
    const int dir = i >> 16;
    const int bm  = i & 0xFFFF;                      // b*N + m
    const float* dst = dir ? pred : gt;
    const float x = dst[3*bm+0], y = dst[3*bm+1], z = dst[3*bm+2];
    const unsigned short hx = bf16_rne(x), hy = bf16_rne(y), hz = bf16_rne(z);
    const unsigned short lx = bf16_rne(x - bf16f(hx));
    const unsigned short ly = bf16_rne(y - bf16f(hy));
    const unsigned short lz = bf16_rne(z - bf16f(hz));
    const float gn = x*x + y*y + z*z;
    const unsigned short gnh = bf16_rne(gn), gnl = bf16_rne(gn - bf16f(gnh));
    const unsigned short one = 0x3F80;

    const int b  = bm >> 13, m = bm & (N_DIM - 1);
    const int mt = m >> 5,   c = m & 31;
    const int dirb = (dir << 3) | b;
    unsigned short* p0 = bpack + ((size_t)(dirb * MT + mt) * 64 + c) * 8;
    unsigned short* p1 = p0 + 32 * 8;
    // half0 = k0..7 : gh(xyz) gl(xyz) gh(x,y) ; half1 = k8..15 : gh(z) 1 1 gnh gnl 0 0 0
    bf16x8 h0 = {(short)hx,(short)hy,(short)hz,(short)lx,(short)ly,(short)lz,(short)hx,(short)hy};
    bf16x8 h1 = {(short)hz,(short)one,(short)one,(short)gnh,(short)gnl,0,0,0};
    *(bf16x8*)p0 = h0;
    *(bf16x8*)p1 = h1;
}

// ---- fused cooperative kernel --------------------------------------------
__global__ __launch_bounds__(BLOCK, 4) void chamfer_fused(
    const float* __restrict__ pred, const float* __restrict__ gt,
    unsigned short* __restrict__ bpack, float* __restrict__ out)
{
    __shared__ float cbuf[PPW * 16 * 128];  // 16 KB combine buffer (epilogue only)
    __shared__ float wsum[2];

    // ---- phase 1: pack B-fragments (1024x256 threads; first 131072 work)
    const int gid = (blockIdx.y * 16 + blockIdx.x) * BLOCK + threadIdx.x;
    if (gid == 0) out[0] = 0.0f;
    if (gid < 2 * B_DIM * N_DIM) pack_point(pred, gt, bpack, gid);
    __threadfence();

    // ---- per-wave setup (raw inputs only; overlaps the grid-sync latency)
    const int dirb = blockIdx.x;            // low grid bits -> XCD = dirb%8
    const int dir  = dirb >> 3, b = dirb & 7;
    const int w    = threadIdx.x >> 6, lane = threadIdx.x & 63;
    const int halfk = lane >> 5,  col = lane & 31;
    const int nsub = w & 1;                 // which n-tile pair
    const int mh   = w >> 1;                // m-half: 0 -> tiles 0..127, 1 -> 128..255

    const float* src  = dir ? gt : pred;
    const float* srcb = src + (size_t)b * N_DIM * 3;

    bf16x8 afrag[PPW];
    #pragma unroll
    for (int p = 0; p < PPW; ++p) {
        const int ntile = blockIdx.y * 4 + nsub * 2 + p;
        const int n = ntile * 32 + col;
        const float x = srcb[3*n+0], y = srcb[3*n+1], z = srcb[3*n+2];
        const float ax = -2.f*x, ay = -2.f*y, az = -2.f*z;
        const unsigned short ahx = bf16_rne(ax), ahy = bf16_rne(ay), ahz = bf16_rne(az);
        const unsigned short alx = bf16_rne(ax - bf16f(ahx));
        const unsigned short aly = bf16_rne(ay - bf16f(ahy));
        const unsigned short alz = bf16_rne(az - bf16f(ahz));
        const float pn = x*x + y*y + z*z;
        const unsigned short pnh = bf16_rne(pn), pnl = bf16_rne(pn - bf16f(pnh));
        const unsigned short one = 0x3F80;
        bf16x8 a0 = {(short)ahx,(short)ahy,(short)ahz,(short)ahx,(short)ahy,(short)ahz,(short)alx,(short)aly};
        bf16x8 a1 = {(short)alz,(short)pnh,(short)pnl,(short)one,(short)one,0,0,0};
        afrag[p] = (halfk == 0) ? a0 : a1;
    }

    float best[PPW][16];
    #pragma unroll
    for (int p = 0; p < PPW; ++p)
        #pragma unroll
        for (int r = 0; r < 16; ++r) best[p][r] = 1e30f;

    // ---- grid-wide sync: bpack fully written & visible
    cg::this_grid().sync();

    // ---- phase 2: stream B-fragments from L2, MFMA + min3 fold (R12 body)
    const bf16x8* bw = (const bf16x8*)bpack
                     + (size_t)dirb * (MT * 64) + (size_t)(mh * 128) * 64 + lane;

    for (int t = 0; t < 64; ++t) {
        const bf16x8 c0 = bw[0];     // m-tile 2t
        const bf16x8 c1 = bw[64];    // m-tile 2t+1
        bw += 128;
        f32x16 d0, d1;
        asm volatile(
            "v_mfma_f32_32x32x16_bf16 %0, %2, %3, 0\n\t"
            "v_mfma_f32_32x32x16_bf16 %1, %2, %4, 0\n\t"
            "s_nop 7\n\t"
            "s_nop 3"
            : "=&v"(d0), "=&v"(d1)
            : "v"(afrag[0]), "v"(c0), "v"(c1));
        __builtin_amdgcn_sched_barrier(0x34);   // VALU may not cross; VMEM/SALU may
        #pragma unroll
        for (int r = 0; r < 16; ++r)
            best[0][r] = fminf(fminf(best[0][r], d0[r]), d1[r]);  // v_min3_f32
        f32x16 d2, d3;
        asm volatile(
            "v_mfma_f32_32x32x16_bf16 %0, %2, %3, 0\n\t"
            "v_mfma_f32_32x32x16_bf16 %1, %2, %4, 0\n\t"
            "s_nop 7\n\t"
            "s_nop 3"
            : "=&v"(d2), "=&v"(d3)
            : "v"(afrag[1]), "v"(c0), "v"(c1));
        __builtin_amdgcn_sched_barrier(0x34);
        #pragma unroll
        for (int r = 0; r < 16; ++r)
            best[1][r] = fminf(fminf(best[1][r], d2[r]), d3[r]);
    }

    // ---- epilogue: combine m-halves via LDS, lane-reduce, one atomicAdd
    if (mh == 1) {
        #pragma unroll
        for (int p = 0; p < PPW; ++p)
            #pragma unroll
            for (int r = 0; r < 16; ++r)
                cbuf[(p * 16 + r) * 128 + nsub * 64 + lane] = best[p][r];
    }
    __syncthreads();
    if (mh == 0) {
        float bsum = 0.f;
        #pragma unroll
        for (int p = 0; p < PPW; ++p) {
            float s = 0.f;
            #pragma unroll
            for (int r = 0; r < 16; ++r) {
                float v = fminf(best[p][r], cbuf[(p * 16 + r) * 128 + nsub * 64 + lane]);
                v = fminf(v, __shfl_xor(v, 1,  64));
                v = fminf(v, __shfl_xor(v, 2,  64));
                v = fminf(v, __shfl_xor(v, 4,  64));
                v = fminf(v, __shfl_xor(v, 8,  64));
                v = fminf(v, __shfl_xor(v, 16, 64));
                s += v;                       // 16 final row-mins of this k-half
            }
            bsum += s + __shfl_xor(s, 32, 64);  // add other k-half's 16 rows
        }
        if (lane == 0) wsum[nsub] = bsum;
    }
    __syncthreads();
    if (threadIdx.x == 0) {
        const float scale = 100.0f * 0.5f / ((float)B_DIM * (float)N_DIM);
        atomicAdd(out, (wsum[0] + wsum[1]) * scale);
    }
}

// ---- fallback two-kernel path (R12-proven) -------------------------------
__global__ __launch_bounds__(256) void chamfer_prep(
    const float* __restrict__ pred, const float* __restrict__ gt,
    unsigned short* __restrict__ bpack, float* __restrict__ out)
{
    const int i = blockIdx.x * 256 + threadIdx.x;
    if (i == 0) out[0] = 0.0f;
    pack_point(pred, gt, bpack, i);
}

__global__ __launch_bounds__(BLOCK, 4) void chamfer_partial(
    const float* __restrict__ pred, const float* __restrict__ gt,
    const bf16x8* __restrict__ bpack, float* __restrict__ out)
{
    __shared__ float cbuf[PPW * 16 * 128];
    __shared__ float wsum[2];
    const int dirb = blockIdx.x;
    const int dir  = dirb >> 3, b = dirb & 7;
    const int w    = threadIdx.x >> 6, lane = threadIdx.x & 63;
    const int halfk = lane >> 5,  col = lane & 31;
    const int nsub = w & 1;
    const int mh   = w >> 1;

    const float* src  = dir ? gt : pred;
    const float* srcb = src + (size_t)b * N_DIM * 3;

    bf16x8 afrag[PPW];
    #pragma unroll
    for (int p = 0; p < PPW; ++p) {
        const int ntile = blockIdx.y * 4 + nsub * 2 + p;
        const int n = ntile * 32 + col;
        const float x = srcb[3*n+0], y = srcb[3*n+1], z = srcb[3*n+2];
        const float ax = -2.f*x, ay = -2.f*y, az = -2.f*z;
        const unsigned short ahx = bf16_rne(ax), ahy = bf16_rne(ay), ahz = bf16_rne(az);
        const unsigned short alx = bf16_rne(ax - bf16f(ahx));
        const unsigned short aly = bf16_rne(ay - bf16f(ahy));
        const unsigned short alz = bf16_rne(az - bf16f(ahz));
        const float pn = x*x + y*y + z*z;
        const unsigned short pnh = bf16_rne(pn), pnl = bf16_rne(pn - bf16f(pnh));
        const unsigned short one = 0x3F80;
        bf16x8 a0 = {(short)ahx,(short)ahy,(short)ahz,(short)ahx,(short)ahy,(short)ahz,(short)alx,(short)aly};
        bf16x8 a1 = {(short)alz,(short)pnh,(short)pnl,(short)one,(short)one,0,0,0};
        afrag[p] = (halfk == 0) ? a0 : a1;
    }

    float best[PPW][16];
    #pragma unroll
    for (int p = 0; p < PPW; ++p)
        #pragma unroll
        for (int r = 0; r < 16; ++r) best[p][r] = 1e30f;

    const bf16x8* bw = bpack + (size_t)dirb * (MT * 64) + (size_t)(mh * 128) * 64 + lane;

    for (int t = 0; t < 64; ++t) {
        const bf16x8 c0 = bw[0];
        const bf16x8 c1 = bw[64];
        bw += 128;
        f32x16 d0, d1;
        asm volatile(
            "v_mfma_f32_32x32x16_bf16 %0, %2, %3, 0\n\t"
            "v_mfma_f32_32x32x16_bf16 %1, %2, %4, 0\n\t"
            "s_nop 7\n\t"
            "s_nop 3"
            : "=&v"(d0), "=&v"(d1)
            : "v"(afrag[0]), "v"(c0), "v"(c1));
        __builtin_amdgcn_sched_barrier(0x34);
        #pragma unroll
        for (int r = 0; r < 16; ++r)
            best[0][r] = fminf(fminf(best[0][r], d0[r]), d1[r]);
        f32x16 d2, d3;
        asm volatile(
            "v_mfma_f32_32x32x16_bf16 %0, %2, %3, 0\n\t"
            "v_mfma_f32_32x32x16_bf16 %1, %2, %4, 0\n\t"
            "s_nop 7\n\t"
            "s_nop 3"
            : "=&v"(d2), "=&v"(d3)
            : "v"(afrag[1]), "v"(c0), "v"(c1));
        __builtin_amdgcn_sched_barrier(0x34);
        #pragma unroll
        for (int r = 0; r < 16; ++r)
            best[1][r] = fminf(fminf(best[1][r], d2[r]), d3[r]);
    }

    if (mh == 1) {
        #pragma unroll
        for (int p = 0; p < PPW; ++p)
            #pragma unroll
            for (int r = 0; r < 16; ++r)
                cbuf[(p * 16 + r) * 128 + nsub * 64 + lane] = best[p][r];
    }
    __syncthreads();
    if (mh == 0) {
        float bsum = 0.f;
        #pragma unroll
        for (int p = 0; p < PPW; ++p) {
            float s = 0.f;
            #pragma unroll
            for (int r = 0; r < 16; ++r) {
                float v = fminf(best[p][r], cbuf[(p * 16 + r) * 128 + nsub * 64 + lane]);
                v = fminf(v, __shfl_xor(v, 1,  64));
                v = fminf(v, __shfl_xor(v, 2,  64));
                v = fminf(v, __shfl_xor(v, 4,  64));
                v = fminf(v, __shfl_xor(v, 8,  64));
                v = fminf(v, __shfl_xor(v, 16, 64));
                s += v;
            }
            bsum += s + __shfl_xor(s, 32, 64);
        }
        if (lane == 0) wsum[nsub] = bsum;
    }
    __syncthreads();
    if (threadIdx.x == 0) {
        const float scale = 100.0f * 0.5f / ((float)B_DIM * (float)N_DIM);
        atomicAdd(out, (wsum[0] + wsum[1]) * scale);
    }
}

extern "C" void kernel_launch(void* const* d_in, const int* in_sizes, int n_in,
                              void* d_out, int out_size, void* d_ws, size_t ws_size,
                              hipStream_t stream) {
    const float* pred = (const float*)d_in[0];
    const float* gt   = (const float*)d_in[1];
    float* out = (float*)d_out;
    unsigned short* bpack = (unsigned short*)d_ws;   // 4 MiB

    void* args[4] = {(void*)&pred, (void*)&gt, (void*)&bpack, (void*)&out};
    hipError_t err = hipLaunchCooperativeKernel(
        (const void*)chamfer_fused, dim3(16, N_DIM / 128), dim3(BLOCK),
        args, 0, stream);
    if (err != hipSuccess) {
        // fallback: proven two-kernel path
        chamfer_prep<<<(2 * B_DIM * N_DIM) / 256, 256, 0, stream>>>(pred, gt, bpack, out);
        dim3 grid(16, N_DIM / 128);
        chamfer_partial<<<grid, BLOCK, 0, stream>>>(pred, gt, (const bf16x8*)bpack, out);
    }
}

// Round 7
// 96.388 us; speedup vs baseline: 2.4742x; 2.4742x over previous
//
#include <hip/hip_runtime.h>

// Chamfer distance: B=8, N=M=8192, D=3, fp32, via bf16 split-precision MFMA.
// R14: R13 post-mortem: (1) cooperative fusion = 175us — same busy work,
//   +120us stall: phase-1 writes scatter across XCDs, so phase-2 reads hit
//   dirty-remote-L2/L3 instead of warm local L2; kernel boundary was doing
//   real work (drain + local reload). (2) overhead is ~50-60us FIXED
//   (238-175=63 with ONE node) -> node count is not a lever. Revert to the
//   two-kernel R12 path.
//   Remaining lever: best[] is AGPR-resident (VGPR_Count=44) -> fold costs
//   17.7us (accvgpr_read/min/accvgpr_write) vs 6.8us fused floor.
//   Fix: fold as per-element asm v_min3 with "+v"/"v" constraints —
//   v-class is arch-VGPR-only (AGPR is "a" class), so best/d are FORCED
//   arch-resident. Hazard is covered by s_nop 7+3 INSIDE the producing
//   MFMA asm (R12-proven; R11's failure was builtin-MFMA -> asm-read with
//   no guard). Plus distance-1 prefetch (n0,n1) to decouple L2 load from
//   consume. Budget: best 32 + d 32 + c/n 32 + afrag 8 + addr ~= 112 < 128
//   @ launch_bounds(256,4).
//   Floors: per-XCD L2 stream ~10-15us, VALU ~6.8us, MFMA ~3.4us.

#define B_DIM 8
#define N_DIM 8192
#define MT    (N_DIM / 32)      // 256 m-tiles per (dir,b)
#define BLOCK 256
#define PPW   2                 // n-tiles per wave

typedef short  bf16x8 __attribute__((ext_vector_type(8)));
typedef float  f32x16 __attribute__((ext_vector_type(16)));

__device__ __forceinline__ unsigned short bf16_rne(float f) {
    unsigned int u = __float_as_uint(f);
    u += 0x7fffu + ((u >> 16) & 1u);
    return (unsigned short)(u >> 16);
}
__device__ __forceinline__ float bf16f(unsigned short h) {
    return __uint_as_float(((unsigned int)h) << 16);
}

// Pack B-fragments for both directions. Layout: 16-byte frags indexed
// [dirb][mtile][half][m32] so a wave's 64 lanes read 1024 contiguous bytes.
__global__ __launch_bounds__(256) void chamfer_prep(
    const float* __restrict__ pred, const float* __restrict__ gt,
    unsigned short* __restrict__ bpack, float* __restrict__ out)
{
    const int i   = blockIdx.x * 256 + threadIdx.x;  // 0 .. 2*B*N-1
    if (i == 0) out[0] = 0.0f;
    const int dir = i >> 16;
    const int bm  = i & 0xFFFF;                      // b*N + m
    const float* dst = dir ? pred : gt;
    const float x = dst[3*bm+0], y = dst[3*bm+1], z = dst[3*bm+2];
    const unsigned short hx = bf16_rne(x), hy = bf16_rne(y), hz = bf16_rne(z);
    const unsigned short lx = bf16_rne(x - bf16f(hx));
    const unsigned short ly = bf16_rne(y - bf16f(hy));
    const unsigned short lz = bf16_rne(z - bf16f(hz));
    const float gn = x*x + y*y + z*z;
    const unsigned short gnh = bf16_rne(gn), gnl = bf16_rne(gn - bf16f(gnh));
    const unsigned short one = 0x3F80;

    const int b  = bm >> 13, m = bm & (N_DIM - 1);
    const int mt = m >> 5,   c = m & 31;
    const int dirb = (dir << 3) | b;
    unsigned short* p0 = bpack + ((size_t)(dirb * MT + mt) * 64 + c) * 8;
    unsigned short* p1 = p0 + 32 * 8;
    // half0 = k0..7 : gh(xyz) gl(xyz) gh(x,y) ; half1 = k8..15 : gh(z) 1 1 gnh gnl 0 0 0
    bf16x8 h0 = {(short)hx,(short)hy,(short)hz,(short)lx,(short)ly,(short)lz,(short)hx,(short)hy};
    bf16x8 h1 = {(short)hz,(short)one,(short)one,(short)gnh,(short)gnl,0,0,0};
    *(bf16x8*)p0 = h0;
    *(bf16x8*)p1 = h1;
}

__global__ __launch_bounds__(BLOCK, 4) void chamfer_partial(
    const float* __restrict__ pred, const float* __restrict__ gt,
    const bf16x8* __restrict__ bpack, float* __restrict__ out)
{
    __shared__ float cbuf[PPW * 16 * 128];  // 16 KB combine buffer (epilogue only)
    __shared__ float wsum[2];
    const int dirb = blockIdx.x;            // low grid bits -> XCD = dirb%8
    const int dir  = dirb >> 3, b = dirb & 7;
    const int w    = threadIdx.x >> 6, lane = threadIdx.x & 63;
    const int halfk = lane >> 5,  col = lane & 31;
    const int nsub = w & 1;                 // which n-tile pair
    const int mh   = w >> 1;                // m-half: 0 -> tiles 0..127, 1 -> 128..255

    const float* src  = dir ? gt : pred;
    const float* srcb = src + (size_t)b * N_DIM * 3;

    // A fragments for this wave's PPW n-tiles (row = col, k-half = halfk).
    bf16x8 afrag[PPW];
    #pragma unroll
    for (int p = 0; p < PPW; ++p) {
        const int ntile = blockIdx.y * 4 + nsub * 2 + p;
        const int n = ntile * 32 + col;
        const float x = srcb[3*n+0], y = srcb[3*n+1], z = srcb[3*n+2];
        const float ax = -2.f*x, ay = -2.f*y, az = -2.f*z;
        const unsigned short ahx = bf16_rne(ax), ahy = bf16_rne(ay), ahz = bf16_rne(az);
        const unsigned short alx = bf16_rne(ax - bf16f(ahx));
        const unsigned short aly = bf16_rne(ay - bf16f(ahy));
        const unsigned short alz = bf16_rne(az - bf16f(ahz));
        const float pn = x*x + y*y + z*z;
        const unsigned short pnh = bf16_rne(pn), pnl = bf16_rne(pn - bf16f(pnh));
        const unsigned short one = 0x3F80;
        bf16x8 a0 = {(short)ahx,(short)ahy,(short)ahz,(short)ahx,(short)ahy,(short)ahz,(short)alx,(short)aly};
        bf16x8 a1 = {(short)alz,(short)pnh,(short)pnl,(short)one,(short)one,0,0,0};
        afrag[p] = (halfk == 0) ? a0 : a1;
    }

    float best[PPW][16];
    #pragma unroll
    for (int p = 0; p < PPW; ++p)
        #pragma unroll
        for (int r = 0; r < 16; ++r) best[p][r] = 1e30f;

    // This wave's B-fragment stream: 128 m-tiles, 1 KB (wave) per tile,
    // coalesced dwordx4 per lane, L2-resident.
    const bf16x8* bw = bpack + (size_t)dirb * (MT * 64) + (size_t)(mh * 128) * 64 + lane;

    // MFMA pair in asm (C = inline 0; s_nop 7+3 inside covers the
    // MFMA->VALU read hazard — R12-proven), then per-element asm v_min3:
    // "+v"/"v" constraints force best/d into arch VGPRs (AGPR is class
    // "a"), killing the accvgpr round-trips that capped R12 at 52us.
#define FOLD(c0_, c1_) { \
        f32x16 d0, d1; \
        asm volatile( \
            "v_mfma_f32_32x32x16_bf16 %0, %2, %3, 0\n\t" \
            "v_mfma_f32_32x32x16_bf16 %1, %2, %4, 0\n\t" \
            "s_nop 7\n\t" \
            "s_nop 3" \
            : "=&v"(d0), "=&v"(d1) \
            : "v"(afrag[0]), "v"(c0_), "v"(c1_)); \
        _Pragma("unroll") \
        for (int r = 0; r < 16; ++r) \
            asm("v_min3_f32 %0, %0, %1, %2" \
                : "+v"(best[0][r]) : "v"(d0[r]), "v"(d1[r])); \
        f32x16 d2, d3; \
        asm volatile( \
            "v_mfma_f32_32x32x16_bf16 %0, %2, %3, 0\n\t" \
            "v_mfma_f32_32x32x16_bf16 %1, %2, %4, 0\n\t" \
            "s_nop 7\n\t" \
            "s_nop 3" \
            : "=&v"(d2), "=&v"(d3) \
            : "v"(afrag[1]), "v"(c0_), "v"(c1_)); \
        _Pragma("unroll") \
        for (int r = 0; r < 16; ++r) \
            asm("v_min3_f32 %0, %0, %1, %2" \
                : "+v"(best[1][r]) : "v"(d2[r]), "v"(d3[r])); \
    }

    bf16x8 c0 = bw[0], c1 = bw[64];
    for (int t = 0; t < 63; ++t) {
        bw += 128;
        const bf16x8 n0 = bw[0];     // distance-1 prefetch of next tile-pair
        const bf16x8 n1 = bw[64];
        FOLD(c0, c1);
        c0 = n0; c1 = n1;
    }
    FOLD(c0, c1);                    // peeled last iteration, no prefetch

    // Combine the two m-halves: waves 2,3 export best[] through LDS,
    // waves 0,1 min-combine. Lanes contiguous -> conflict-free.
    if (mh == 1) {
        #pragma unroll
        for (int p = 0; p < PPW; ++p)
            #pragma unroll
            for (int r = 0; r < 16; ++r)
                cbuf[(p * 16 + r) * 128 + nsub * 64 + lane] = best[p][r];
    }
    __syncthreads();
    if (mh == 0) {
        float bsum = 0.f;
        #pragma unroll
        for (int p = 0; p < PPW; ++p) {
            float s = 0.f;
            #pragma unroll
            for (int r = 0; r < 16; ++r) {
                float v = fminf(best[p][r], cbuf[(p * 16 + r) * 128 + nsub * 64 + lane]);
                v = fminf(v, __shfl_xor(v, 1,  64));
                v = fminf(v, __shfl_xor(v, 2,  64));
                v = fminf(v, __shfl_xor(v, 4,  64));
                v = fminf(v, __shfl_xor(v, 8,  64));
                v = fminf(v, __shfl_xor(v, 16, 64));
                s += v;                       // 16 final row-mins of this k-half
            }
            bsum += s + __shfl_xor(s, 32, 64);  // add other k-half's 16 rows
        }
        if (lane == 0) wsum[nsub] = bsum;
    }
    __syncthreads();
    if (threadIdx.x == 0) {
        const float scale = 100.0f * 0.5f / ((float)B_DIM * (float)N_DIM);
        atomicAdd(out, (wsum[0] + wsum[1]) * scale);
    }
}

extern "C" void kernel_launch(void* const* d_in, const int* in_sizes, int n_in,
                              void* d_out, int out_size, void* d_ws, size_t ws_size,
                              hipStream_t stream) {
    const float* pred = (const float*)d_in[0];
    const float* gt   = (const float*)d_in[1];
    float* out = (float*)d_out;
    unsigned short* bpack = (unsigned short*)d_ws;   // 4 MiB

    chamfer_prep<<<(2 * B_DIM * N_DIM) / 256, 256, 0, stream>>>(pred, gt, bpack, out);

    // dirb x n-chunks(128 pts) = 16 x 64 = 1024 blocks, 4 indep waves each
    dim3 grid(16, N_DIM / 128);
    chamfer_partial<<<grid, BLOCK, 0, stream>>>(pred, gt, (const bf16x8*)bpack, out);
}

// Round 8
// 93.666 us; speedup vs baseline: 2.5461x; 1.0291x over previous
//
#include <hip/hip_runtime.h>

// Chamfer distance: B=8, N=M=8192, D=3, fp32, via bf16 split-precision MFMA.
// R15: R14 post-mortem: (1) AGPR theory dead — "+v" can't bind AGPRs, so
//   R14's fold provably ran on arch VGPRs and time didn't move; VGPR_Count
//   is in 2-reg units (R8 "64"=128=cap ✓, R14 "48"=96 ✓). (2) Occupancy
//   26% on the /64-wave gfx94x formula = 16 waves/CU = fully resident.
//   Wall 48.4 vs busy pipes ~13 VALU + 3.4 MFMA + ~7 VMEM -> waves are
//   parked in s_waitcnt vmcnt. Cause: the loop tail copies c0=n0;c1=n1
//   force vmcnt(0) in the SAME iteration that issued the loads (~80cy
//   separation vs ~300cy loaded-L2 latency) -> ~200 stall cyc/iter/wave.
//   Same defect in every 45-52us variant (R7's rg ferry included).
//   Fix (ONE change): copy-free x2 ping-pong — two pairs cA/cB; each pair
//   reloads into ITS OWN registers right after the FOLD that kills them
//   (WAR enforces order, no copies), consumed one full phase later:
//   separation ~350-400cy across 4 interleaved waves. Immediate offsets
//   0/1KB/2KB/3KB, one bw+=256 per 2 phases (kills 16 movs + addr VALU).
//   FOLD macro, grid, epilogue: R14-identical (proven absmax 0).

#define B_DIM 8
#define N_DIM 8192
#define MT    (N_DIM / 32)      // 256 m-tiles per (dir,b)
#define BLOCK 256
#define PPW   2                 // n-tiles per wave

typedef short  bf16x8 __attribute__((ext_vector_type(8)));
typedef float  f32x16 __attribute__((ext_vector_type(16)));

__device__ __forceinline__ unsigned short bf16_rne(float f) {
    unsigned int u = __float_as_uint(f);
    u += 0x7fffu + ((u >> 16) & 1u);
    return (unsigned short)(u >> 16);
}
__device__ __forceinline__ float bf16f(unsigned short h) {
    return __uint_as_float(((unsigned int)h) << 16);
}

// Pack B-fragments for both directions. Layout: 16-byte frags indexed
// [dirb][mtile][half][m32] so a wave's 64 lanes read 1024 contiguous bytes.
__global__ __launch_bounds__(256) void chamfer_prep(
    const float* __restrict__ pred, const float* __restrict__ gt,
    unsigned short* __restrict__ bpack, float* __restrict__ out)
{
    const int i   = blockIdx.x * 256 + threadIdx.x;  // 0 .. 2*B*N-1
    if (i == 0) out[0] = 0.0f;
    const int dir = i >> 16;
    const int bm  = i & 0xFFFF;                      // b*N + m
    const float* dst = dir ? pred : gt;
    const float x = dst[3*bm+0], y = dst[3*bm+1], z = dst[3*bm+2];
    const unsigned short hx = bf16_rne(x), hy = bf16_rne(y), hz = bf16_rne(z);
    const unsigned short lx = bf16_rne(x - bf16f(hx));
    const unsigned short ly = bf16_rne(y - bf16f(hy));
    const unsigned short lz = bf16_rne(z - bf16f(hz));
    const float gn = x*x + y*y + z*z;
    const unsigned short gnh = bf16_rne(gn), gnl = bf16_rne(gn - bf16f(gnh));
    const unsigned short one = 0x3F80;

    const int b  = bm >> 13, m = bm & (N_DIM - 1);
    const int mt = m >> 5,   c = m & 31;
    const int dirb = (dir << 3) | b;
    unsigned short* p0 = bpack + ((size_t)(dirb * MT + mt) * 64 + c) * 8;
    unsigned short* p1 = p0 + 32 * 8;
    // half0 = k0..7 : gh(xyz) gl(xyz) gh(x,y) ; half1 = k8..15 : gh(z) 1 1 gnh gnl 0 0 0
    bf16x8 h0 = {(short)hx,(short)hy,(short)hz,(short)lx,(short)ly,(short)lz,(short)hx,(short)hy};
    bf16x8 h1 = {(short)hz,(short)one,(short)one,(short)gnh,(short)gnl,0,0,0};
    *(bf16x8*)p0 = h0;
    *(bf16x8*)p1 = h1;
}

__global__ __launch_bounds__(BLOCK, 4) void chamfer_partial(
    const float* __restrict__ pred, const float* __restrict__ gt,
    const bf16x8* __restrict__ bpack, float* __restrict__ out)
{
    __shared__ float cbuf[PPW * 16 * 128];  // 16 KB combine buffer (epilogue only)
    __shared__ float wsum[2];
    const int dirb = blockIdx.x;            // low grid bits -> XCD = dirb%8
    const int dir  = dirb >> 3, b = dirb & 7;
    const int w    = threadIdx.x >> 6, lane = threadIdx.x & 63;
    const int halfk = lane >> 5,  col = lane & 31;
    const int nsub = w & 1;                 // which n-tile pair
    const int mh   = w >> 1;                // m-half: 0 -> tiles 0..127, 1 -> 128..255

    const float* src  = dir ? gt : pred;
    const float* srcb = src + (size_t)b * N_DIM * 3;

    // A fragments for this wave's PPW n-tiles (row = col, k-half = halfk).
    bf16x8 afrag[PPW];
    #pragma unroll
    for (int p = 0; p < PPW; ++p) {
        const int ntile = blockIdx.y * 4 + nsub * 2 + p;
        const int n = ntile * 32 + col;
        const float x = srcb[3*n+0], y = srcb[3*n+1], z = srcb[3*n+2];
        const float ax = -2.f*x, ay = -2.f*y, az = -2.f*z;
        const unsigned short ahx = bf16_rne(ax), ahy = bf16_rne(ay), ahz = bf16_rne(az);
        const unsigned short alx = bf16_rne(ax - bf16f(ahx));
        const unsigned short aly = bf16_rne(ay - bf16f(ahy));
        const unsigned short alz = bf16_rne(az - bf16f(ahz));
        const float pn = x*x + y*y + z*z;
        const unsigned short pnh = bf16_rne(pn), pnl = bf16_rne(pn - bf16f(pnh));
        const unsigned short one = 0x3F80;
        bf16x8 a0 = {(short)ahx,(short)ahy,(short)ahz,(short)ahx,(short)ahy,(short)ahz,(short)alx,(short)aly};
        bf16x8 a1 = {(short)alz,(short)pnh,(short)pnl,(short)one,(short)one,0,0,0};
        afrag[p] = (halfk == 0) ? a0 : a1;
    }

    float best[PPW][16];
    #pragma unroll
    for (int p = 0; p < PPW; ++p)
        #pragma unroll
        for (int r = 0; r < 16; ++r) best[p][r] = 1e30f;

    // This wave's B-fragment stream: 128 m-tiles, 1 KB (wave) per tile,
    // coalesced dwordx4 per lane, L2-resident.
    const bf16x8* bw = bpack + (size_t)dirb * (MT * 64) + (size_t)(mh * 128) * 64 + lane;

    // MFMA pair in asm (C = inline 0; s_nop 7+3 inside covers the
    // MFMA->VALU read hazard), then per-element asm v_min3 on arch VGPRs.
    // R14-proven correct (absmax 0).
#define FOLD(c0_, c1_) { \
        f32x16 d0, d1; \
        asm volatile( \
            "v_mfma_f32_32x32x16_bf16 %0, %2, %3, 0\n\t" \
            "v_mfma_f32_32x32x16_bf16 %1, %2, %4, 0\n\t" \
            "s_nop 7\n\t" \
            "s_nop 3" \
            : "=&v"(d0), "=&v"(d1) \
            : "v"(afrag[0]), "v"(c0_), "v"(c1_)); \
        _Pragma("unroll") \
        for (int r = 0; r < 16; ++r) \
            asm("v_min3_f32 %0, %0, %1, %2" \
                : "+v"(best[0][r]) : "v"(d0[r]), "v"(d1[r])); \
        f32x16 d2, d3; \
        asm volatile( \
            "v_mfma_f32_32x32x16_bf16 %0, %2, %3, 0\n\t" \
            "v_mfma_f32_32x32x16_bf16 %1, %2, %4, 0\n\t" \
            "s_nop 7\n\t" \
            "s_nop 3" \
            : "=&v"(d2), "=&v"(d3) \
            : "v"(afrag[1]), "v"(c0_), "v"(c1_)); \
        _Pragma("unroll") \
        for (int r = 0; r < 16; ++r) \
            asm("v_min3_f32 %0, %0, %1, %2" \
                : "+v"(best[1][r]) : "v"(d2[r]), "v"(d3[r])); \
    }

    // Copy-free x2 ping-pong: 64 tile-pair phases P0..P63.
    // Prologue loads P0 (tiles 0,1) and P1 (tiles 2,3); each loop iter
    // folds two phases and reloads each pair right after its fold
    // (WAR on the same registers orders load after consume; consumed one
    // full phase later -> load->use separation ~a FOLD x 4 waves).
    bf16x8 cA0 = bw[0],   cA1 = bw[64];    // P0
    bf16x8 cB0 = bw[128], cB1 = bw[192];   // P1
    bw += 256;
    for (int t = 0; t < 31; ++t) {
        FOLD(cA0, cA1);                    // fold P{2t}
        cA0 = bw[0];   cA1 = bw[64];       // load P{2t+2}
        FOLD(cB0, cB1);                    // fold P{2t+1}
        cB0 = bw[128]; cB1 = bw[192];      // load P{2t+3}
        bw += 256;
    }
    FOLD(cA0, cA1);                        // P62
    FOLD(cB0, cB1);                        // P63

    // Combine the two m-halves: waves 2,3 export best[] through LDS,
    // waves 0,1 min-combine. Lanes contiguous -> conflict-free.
    if (mh == 1) {
        #pragma unroll
        for (int p = 0; p < PPW; ++p)
            #pragma unroll
            for (int r = 0; r < 16; ++r)
                cbuf[(p * 16 + r) * 128 + nsub * 64 + lane] = best[p][r];
    }
    __syncthreads();
    if (mh == 0) {
        float bsum = 0.f;
        #pragma unroll
        for (int p = 0; p < PPW; ++p) {
            float s = 0.f;
            #pragma unroll
            for (int r = 0; r < 16; ++r) {
                float v = fminf(best[p][r], cbuf[(p * 16 + r) * 128 + nsub * 64 + lane]);
                v = fminf(v, __shfl_xor(v, 1,  64));
                v = fminf(v, __shfl_xor(v, 2,  64));
                v = fminf(v, __shfl_xor(v, 4,  64));
                v = fminf(v, __shfl_xor(v, 8,  64));
                v = fminf(v, __shfl_xor(v, 16, 64));
                s += v;                       // 16 final row-mins of this k-half
            }
            bsum += s + __shfl_xor(s, 32, 64);  // add other k-half's 16 rows
        }
        if (lane == 0) wsum[nsub] = bsum;
    }
    __syncthreads();
    if (threadIdx.x == 0) {
        const float scale = 100.0f * 0.5f / ((float)B_DIM * (float)N_DIM);
        atomicAdd(out, (wsum[0] + wsum[1]) * scale);
    }
}

extern "C" void kernel_launch(void* const* d_in, const int* in_sizes, int n_in,
                              void* d_out, int out_size, void* d_ws, size_t ws_size,
                              hipStream_t stream) {
    const float* pred = (const float*)d_in[0];
    const float* gt   = (const float*)d_in[1];
    float* out = (float*)d_out;
    unsigned short* bpack = (unsigned short*)d_ws;   // 4 MiB

    chamfer_prep<<<(2 * B_DIM * N_DIM) / 256, 256, 0, stream>>>(pred, gt, bpack, out);

    // dirb x n-chunks(128 pts) = 16 x 64 = 1024 blocks, 4 indep waves each
    dim3 grid(16, N_DIM / 128);
    chamfer_partial<<<grid, BLOCK, 0, stream>>>(pred, gt, (const bf16x8*)bpack, out);
}

// Round 9
// 93.417 us; speedup vs baseline: 2.5529x; 1.0027x over previous
//
#include <hip/hip_runtime.h>

// Chamfer distance: B=8, N=M=8192, D=3, fp32, via bf16 split-precision MFMA.
// R16: R15 post-mortem (corrected pipe model): 32x32x16 MFMA is ~32 cyc
//   per SIMD (m119's 8 cyc is per-CU) -> MFMA pipe demand = 13.7us and
//   MfmaUtil 32.6% x 43.7us = 14.2us MATCHES: the MFMA floor is ~14us and
//   is irreducible (K=16 minimal; 34.4 GFLOP @ 2.5PF). Second pipe:
//   aggregate L2 = 4096 waves x 128KB = 512MB -> ~15us floor. Two ~15us
//   floors poorly overlapped = 43.7 wall.
//   Lever: arithmetic intensity. PPW 2 -> 4: each B-fragment load feeds 4
//   MFMAs -> L2 traffic halves to 256MB (floor ~8-10us); per-phase FOLD
//   doubles (8 MFMAs) -> load->use separation ~400+cyc covers loaded-L2
//   latency even at 1 wave; 4 independent best-banks give in-wave ILP to
//   replace lost TLP. Grid (16,32) = 512 blocks = 2 blocks/CU = 2 w/SIMD.
//   Registers: best 64 + d 32 (reused per p) + c 16 + afrag 16 + addr
//   ~= 140 -> launch_bounds(256,3) caps at ~168 (R8 lesson: never cap
//   below demand). MFMA/SIMD unchanged; VALU unchanged 6.8us.
//   FOLD asm pattern (MFMA pair + s_nop 7/3 + v_min3 "+v") is the
//   R14/R15-proven-correct producer/consumer split.

#define B_DIM 8
#define N_DIM 8192
#define MT    (N_DIM / 32)      // 256 m-tiles per (dir,b)
#define BLOCK 256
#define PPW   4                 // n-tiles per wave

typedef short  bf16x8 __attribute__((ext_vector_type(8)));
typedef float  f32x16 __attribute__((ext_vector_type(16)));

__device__ __forceinline__ unsigned short bf16_rne(float f) {
    unsigned int u = __float_as_uint(f);
    u += 0x7fffu + ((u >> 16) & 1u);
    return (unsigned short)(u >> 16);
}
__device__ __forceinline__ float bf16f(unsigned short h) {
    return __uint_as_float(((unsigned int)h) << 16);
}

// Pack B-fragments for both directions. Layout: 16-byte frags indexed
// [dirb][mtile][half][m32] so a wave's 64 lanes read 1024 contiguous bytes.
__global__ __launch_bounds__(256) void chamfer_prep(
    const float* __restrict__ pred, const float* __restrict__ gt,
    unsigned short* __restrict__ bpack, float* __restrict__ out)
{
    const int i   = blockIdx.x * 256 + threadIdx.x;  // 0 .. 2*B*N-1
    if (i == 0) out[0] = 0.0f;
    const int dir = i >> 16;
    const int bm  = i & 0xFFFF;                      // b*N + m
    const float* dst = dir ? pred : gt;
    const float x = dst[3*bm+0], y = dst[3*bm+1], z = dst[3*bm+2];
    const unsigned short hx = bf16_rne(x), hy = bf16_rne(y), hz = bf16_rne(z);
    const unsigned short lx = bf16_rne(x - bf16f(hx));
    const unsigned short ly = bf16_rne(y - bf16f(hy));
    const unsigned short lz = bf16_rne(z - bf16f(hz));
    const float gn = x*x + y*y + z*z;
    const unsigned short gnh = bf16_rne(gn), gnl = bf16_rne(gn - bf16f(gnh));
    const unsigned short one = 0x3F80;

    const int b  = bm >> 13, m = bm & (N_DIM - 1);
    const int mt = m >> 5,   c = m & 31;
    const int dirb = (dir << 3) | b;
    unsigned short* p0 = bpack + ((size_t)(dirb * MT + mt) * 64 + c) * 8;
    unsigned short* p1 = p0 + 32 * 8;
    // half0 = k0..7 : gh(xyz) gl(xyz) gh(x,y) ; half1 = k8..15 : gh(z) 1 1 gnh gnl 0 0 0
    bf16x8 h0 = {(short)hx,(short)hy,(short)hz,(short)lx,(short)ly,(short)lz,(short)hx,(short)hy};
    bf16x8 h1 = {(short)hz,(short)one,(short)one,(short)gnh,(short)gnl,0,0,0};
    *(bf16x8*)p0 = h0;
    *(bf16x8*)p1 = h1;
}

__global__ __launch_bounds__(BLOCK, 3) void chamfer_partial(
    const float* __restrict__ pred, const float* __restrict__ gt,
    const bf16x8* __restrict__ bpack, float* __restrict__ out)
{
    __shared__ float cbuf[PPW * 16 * 128];  // 32 KB combine buffer (epilogue only)
    __shared__ float wsum[2];
    const int dirb = blockIdx.x;            // low grid bits -> XCD = dirb%8
    const int dir  = dirb >> 3, b = dirb & 7;
    const int w    = threadIdx.x >> 6, lane = threadIdx.x & 63;
    const int halfk = lane >> 5,  col = lane & 31;
    const int nsub = w & 1;                 // which n-tile quad
    const int mh   = w >> 1;                // m-half: 0 -> tiles 0..127, 1 -> 128..255

    const float* src  = dir ? gt : pred;
    const float* srcb = src + (size_t)b * N_DIM * 3;

    // A fragments for this wave's PPW n-tiles (row = col, k-half = halfk).
    bf16x8 afrag[PPW];
    #pragma unroll
    for (int p = 0; p < PPW; ++p) {
        const int ntile = blockIdx.y * 8 + nsub * PPW + p;
        const int n = ntile * 32 + col;
        const float x = srcb[3*n+0], y = srcb[3*n+1], z = srcb[3*n+2];
        const float ax = -2.f*x, ay = -2.f*y, az = -2.f*z;
        const unsigned short ahx = bf16_rne(ax), ahy = bf16_rne(ay), ahz = bf16_rne(az);
        const unsigned short alx = bf16_rne(ax - bf16f(ahx));
        const unsigned short aly = bf16_rne(ay - bf16f(ahy));
        const unsigned short alz = bf16_rne(az - bf16f(ahz));
        const float pn = x*x + y*y + z*z;
        const unsigned short pnh = bf16_rne(pn), pnl = bf16_rne(pn - bf16f(pnh));
        const unsigned short one = 0x3F80;
        bf16x8 a0 = {(short)ahx,(short)ahy,(short)ahz,(short)ahx,(short)ahy,(short)ahz,(short)alx,(short)aly};
        bf16x8 a1 = {(short)alz,(short)pnh,(short)pnl,(short)one,(short)one,0,0,0};
        afrag[p] = (halfk == 0) ? a0 : a1;
    }

    float best[PPW][16];
    #pragma unroll
    for (int p = 0; p < PPW; ++p)
        #pragma unroll
        for (int r = 0; r < 16; ++r) best[p][r] = 1e30f;

    // This wave's B-fragment stream: 128 m-tiles, 1 KB (wave) per tile,
    // coalesced dwordx4 per lane, L2-resident.
    const bf16x8* bw = bpack + (size_t)dirb * (MT * 64) + (size_t)(mh * 128) * 64 + lane;

    // Per n-tile p: MFMA pair in asm (C = inline 0; s_nop 7+3 inside
    // covers the MFMA->VALU read hazard), then per-element asm v_min3 on
    // arch VGPRs ("+v" cannot bind AGPRs). R14/R15-proven correct.
    // d0/d1 die after each p -> allocator reuses 32 regs across p.
#define FOLD(c0_, c1_) { \
        _Pragma("unroll") \
        for (int p = 0; p < PPW; ++p) { \
            f32x16 d0, d1; \
            asm volatile( \
                "v_mfma_f32_32x32x16_bf16 %0, %2, %3, 0\n\t" \
                "v_mfma_f32_32x32x16_bf16 %1, %2, %4, 0\n\t" \
                "s_nop 7\n\t" \
                "s_nop 3" \
                : "=&v"(d0), "=&v"(d1) \
                : "v"(afrag[p]), "v"(c0_), "v"(c1_)); \
            _Pragma("unroll") \
            for (int r = 0; r < 16; ++r) \
                asm("v_min3_f32 %0, %0, %1, %2" \
                    : "+v"(best[p][r]) : "v"(d0[r]), "v"(d1[r])); \
        } \
    }

    // Copy-free x2 ping-pong: 64 tile-pair phases P0..P63. Each pair
    // reloads into ITS OWN registers right after the FOLD that kills it
    // (WAR orders load after consume; consumed one full ~8-MFMA phase
    // later -> load->use separation > loaded-L2 latency).
    bf16x8 cA0 = bw[0],   cA1 = bw[64];    // P0
    bf16x8 cB0 = bw[128], cB1 = bw[192];   // P1
    bw += 256;
    for (int t = 0; t < 31; ++t) {
        FOLD(cA0, cA1);                    // fold P{2t}
        cA0 = bw[0];   cA1 = bw[64];       // load P{2t+2}
        FOLD(cB0, cB1);                    // fold P{2t+1}
        cB0 = bw[128]; cB1 = bw[192];      // load P{2t+3}
        bw += 256;
    }
    FOLD(cA0, cA1);                        // P62
    FOLD(cB0, cB1);                        // P63

    // Combine the two m-halves: waves 2,3 export best[] through LDS,
    // waves 0,1 min-combine. Lanes contiguous -> conflict-free.
    if (mh == 1) {
        #pragma unroll
        for (int p = 0; p < PPW; ++p)
            #pragma unroll
            for (int r = 0; r < 16; ++r)
                cbuf[(p * 16 + r) * 128 + nsub * 64 + lane] = best[p][r];
    }
    __syncthreads();
    if (mh == 0) {
        float bsum = 0.f;
        #pragma unroll
        for (int p = 0; p < PPW; ++p) {
            float s = 0.f;
            #pragma unroll
            for (int r = 0; r < 16; ++r) {
                float v = fminf(best[p][r], cbuf[(p * 16 + r) * 128 + nsub * 64 + lane]);
                v = fminf(v, __shfl_xor(v, 1,  64));
                v = fminf(v, __shfl_xor(v, 2,  64));
                v = fminf(v, __shfl_xor(v, 4,  64));
                v = fminf(v, __shfl_xor(v, 8,  64));
                v = fminf(v, __shfl_xor(v, 16, 64));
                s += v;                       // 16 final row-mins of this k-half
            }
            bsum += s + __shfl_xor(s, 32, 64);  // add other k-half's 16 rows
        }
        if (lane == 0) wsum[nsub] = bsum;
    }
    __syncthreads();
    if (threadIdx.x == 0) {
        const float scale = 100.0f * 0.5f / ((float)B_DIM * (float)N_DIM);
        atomicAdd(out, (wsum[0] + wsum[1]) * scale);
    }
}

extern "C" void kernel_launch(void* const* d_in, const int* in_sizes, int n_in,
                              void* d_out, int out_size, void* d_ws, size_t ws_size,
                              hipStream_t stream) {
    const float* pred = (const float*)d_in[0];
    const float* gt   = (const float*)d_in[1];
    float* out = (float*)d_out;
    unsigned short* bpack = (unsigned short*)d_ws;   // 4 MiB

    chamfer_prep<<<(2 * B_DIM * N_DIM) / 256, 256, 0, stream>>>(pred, gt, bpack, out);

    // dirb x n-chunks(256 pts) = 16 x 32 = 512 blocks, 2/CU, 4 indep waves
    dim3 grid(16, N_DIM / 256);
    chamfer_partial<<<grid, BLOCK, 0, stream>>>(pred, gt, (const bf16x8*)bpack, out);
}